// Round 16
// baseline (72.257 us; speedup 1.0000x reference)
//
#include <hip/hip_runtime.h>
#include <math.h>

// Tropical max/min-plus pseudo-matmul.
// out[b,u] = max_f(x[b,f] + w[f,u]) for u<128, min_f otherwise.
//
// R13 measured: purely VALU-issue-bound (VALUBusy 97.5%). R15 (pk diet)
// produced a post-timing nondeterministic divergence; suspect surface was
// the combine-region/x-tile LDS overlap + dual-tile scheduling. R16:
//  - NON-OVERLAPPING LDS: x tile 16KB at 0, combine 64KB at +16KB (80KB
//    total of 160KB). No location is read after being overwritten.
//  - single x tile; per-lane sign via v_pk_fma_f32: s = fma(x, sgn2, w*sgn)
//    = +-(x+w) exactly (+-1 mul exact, single rounding).
//  - packed core via clang elementwise builtins (v_pk_fma_f32/v_pk_max_f32,
//    no inline-asm operand copies): 8 pk_fma + 8 pk_max per quad-row
//    (~0.75x R13's scalar instr count).
// Structure: BR=8, U=4/lane (unit-paired v2f), NW=8 waves k-split KW=64,
// A/B pipelined quads, 256 blocks = 1/CU, 2 waves/SIMD.

#define FEAT  512
#define UNITS 256
#define BR    8          // rows per block
#define KW    64         // k per wave
#define NW    8          // waves per block
#define NQ    (KW / 4)   // 16 quads per wave
#define PART  4096       // float offset of combine region (x tile is [0,4096))

typedef float v2f __attribute__((ext_vector_type(2)));

__device__ __forceinline__ v2f pk_max(v2f a, v2f b) {
    return __builtin_elementwise_max(a, b);     // v_pk_max_f32
}
__device__ __forceinline__ v2f pk_fma(v2f a, v2f b, v2f c) {
    return __builtin_elementwise_fma(a, b, c);  // v_pk_fma_f32
}

__device__ __forceinline__ void load_xquad(const float* __restrict__ lds,
                                           int kb, int q, float4* __restrict__ xb) {
    #pragma unroll
    for (int r = 0; r < BR; ++r)   // broadcast ds_read_b128, one address/wave
        xb[r] = *(const float4*)&lds[r * FEAT + kb + q * 4];
}

// w-quad, sign-folded, unit-paired: wsg[2k+h] = w[k][2h..2h+1] * sgn
__device__ __forceinline__ void load_wquad_sgn(const float* __restrict__ wp, int q,
                                               v2f sgn2, v2f* __restrict__ wsg) {
    #pragma unroll
    for (int k = 0; k < 4; ++k) {
        const float4 wk = *(const float4*)(wp + (size_t)(q * 4 + k) * UNITS);
        wsg[2 * k + 0] = v2f{wk.x, wk.y} * sgn2;   // v_pk_mul_f32
        wsg[2 * k + 1] = v2f{wk.z, wk.w} * sgn2;
    }
}

// acc[r][0] = units (u0,u1), acc[r][1] = units (u2,u3)
__device__ __forceinline__ void compute_quad(const float4* __restrict__ xb,
                                             const v2f* __restrict__ wsg,
                                             v2f sgn2, v2f (*__restrict__ acc)[2]) {
    #pragma unroll
    for (int r = 0; r < BR; ++r) {
        const float4 a = xb[r];
        const v2f a0 = {a.x, a.x};
        const v2f a1 = {a.y, a.y};
        const v2f a2 = {a.z, a.z};
        const v2f a3 = {a.w, a.w};
        // 8 pk_fma: s = +-x + +-w (exact +-(x+w))
        const v2f s0 = pk_fma(a0, sgn2, wsg[0]);
        const v2f t0 = pk_fma(a0, sgn2, wsg[1]);
        const v2f s1 = pk_fma(a1, sgn2, wsg[2]);
        const v2f t1 = pk_fma(a1, sgn2, wsg[3]);
        const v2f s2 = pk_fma(a2, sgn2, wsg[4]);
        const v2f t2 = pk_fma(a2, sgn2, wsg[5]);
        const v2f s3 = pk_fma(a3, sgn2, wsg[6]);
        const v2f t3 = pk_fma(a3, sgn2, wsg[7]);
        // 8 pk_max: merge 16 sums into the 2 packed accs
        acc[r][0] = pk_max(acc[r][0], pk_max(pk_max(s0, s1), pk_max(s2, s3)));
        acc[r][1] = pk_max(acc[r][1], pk_max(pk_max(t0, t1), pk_max(t2, t3)));
    }
}

__global__ __launch_bounds__(512) void tropical_kernel(const float* __restrict__ x,
                                                       const float* __restrict__ w,
                                                       float* __restrict__ out) {
    __shared__ float lds[PART + NW * BR * UNITS];   // 16KB x tile + 64KB combine
    const int tid  = threadIdx.x;
    const int lane = tid & 63;
    const int wv   = __builtin_amdgcn_readfirstlane(tid >> 6);  // 0..7
    const int u0   = lane * 4;                                  // 0..252
    const float sgn = (lane < 32) ? 1.0f : -1.0f;               // min half negated
    const v2f  sgn2 = {sgn, sgn};
    const int row0 = blockIdx.x * BR;
    const int kb   = wv * KW;

    // ---- stage x tile (8 rows x 512 = 16 KB), two float4 per thread ----
    {
        const float4* src = (const float4*)(x + (size_t)row0 * FEAT);
        ((float4*)lds)[tid]       = src[tid];
        ((float4*)lds)[tid + 512] = src[tid + 512];
    }

    const float* wp = w + (size_t)kb * UNITS + u0;

    v2f acc[BR][2];
    #pragma unroll
    for (int r = 0; r < BR; ++r) {
        acc[r][0] = v2f{-__builtin_inff(), -__builtin_inff()};
        acc[r][1] = v2f{-__builtin_inff(), -__builtin_inff()};
    }

    float4 xA[BR], xB[BR];
    v2f wA[8], wB[8];
    load_wquad_sgn(wp, 0, sgn2, wA);

    __syncthreads();   // x tile visible
    load_xquad(lds, kb, 0, xA);

    #pragma unroll 1
    for (int q = 0; q < NQ; q += 2) {
        load_wquad_sgn(wp, q + 1, sgn2, wB);
        load_xquad(lds, kb, q + 1, xB);
        compute_quad(xA, wA, sgn2, acc);
        if (q + 2 < NQ) {
            load_wquad_sgn(wp, q + 2, sgn2, wA);
            load_xquad(lds, kb, q + 2, xA);
        }
        compute_quad(xB, wB, sgn2, acc);
    }

    // ---- combine 8 k-partials in the SEPARATE region (no overlap w/ x) ----
    #pragma unroll
    for (int r = 0; r < BR; ++r)
        *(float4*)&lds[PART + ((wv * BR + r) * UNITS) + u0] =
            make_float4(acc[r][0].x, acc[r][0].y, acc[r][1].x, acc[r][1].y);
    __syncthreads();   // partials visible

    // thread -> float4 of output: r = tid>>6 (0..7), units uo..uo+3
    const int r  = tid >> 6;
    const int uo = (tid & 63) * 4;
    float4 v = *(const float4*)&lds[PART + (0 * BR + r) * UNITS + uo];
    #pragma unroll
    for (int j = 1; j < NW; ++j) {
        const float4 p = *(const float4*)&lds[PART + (j * BR + r) * UNITS + uo];
        v.x = fmaxf(v.x, p.x);
        v.y = fmaxf(v.y, p.y);
        v.z = fmaxf(v.z, p.z);
        v.w = fmaxf(v.w, p.w);
    }
    const float so = (uo < 128) ? 1.0f : -1.0f;    // undo negation for min half
    *(float4*)&out[(size_t)(row0 + r) * UNITS + uo] =
        make_float4(v.x * so, v.y * so, v.z * so, v.w * so);
}

extern "C" void kernel_launch(void* const* d_in, const int* in_sizes, int n_in,
                              void* d_out, int out_size, void* d_ws, size_t ws_size,
                              hipStream_t stream) {
    const float* x = (const float*)d_in[0];   // (2048, 512)
    const float* w = (const float*)d_in[1];   // (512, 256)
    float* out = (float*)d_out;               // (2048, 256)

    // 256 blocks x 8 waves = 2048 waves = 2/SIMD, 1 block/CU
    tropical_kernel<<<dim3(2048 / BR), dim3(512), 0, stream>>>(x, w, out);
}

// Round 17
// 67.870 us; speedup vs baseline: 1.0646x; 1.0646x over previous
//
#include <hip/hip_runtime.h>
#include <math.h>

// Tropical max/min-plus pseudo-matmul — TERMINAL KERNEL (best measured, R12).
// out[b,u] = max_f(x[b,f] + w[f,u]) for u<128, min_f otherwise.
//
// Roofline evidence (R13 diagnostic, reps=6): VALUBusy 97.5%, FETCH 4.1MB
// (= inputs exactly), SQ_LDS_BANK_CONFLICT 0, VGPR 104 (no spill). The
// workload is VALU-issue-bound: tropical MAC = v_fmaf + 0.5*v_max3 =
// 1.5 ops/MAC (algorithmic minimum; MFMA can't express semiring max-reduce).
// Dead levers (all +-2us): occupancy 1->4 waves/SIMD, U 2->4, BR 4->8,
// SW pipelining, packed math (R14/R15/R16: v_pk_*_f32 halves share the
// 32-lane fp32 datapath -> 2x FLOPs in 2x issue cycles, no gain).
// Hard-won toolchain facts: __launch_bounds__ 2nd arg acts CUDA-style
// (blocks/CU) here (R5: (512,4)->64 VGPR spill disaster; R7: (512,2)->128);
// manual multi-buffer + full unroll => load hoisting => spill (R7).
//
// Structure: BR=8 rows/block, U=4 units/lane (wave covers all 256 units),
// NW=8 waves k-split (KW=64), x broadcast from LDS (ds_read_b128, one
// address/wave), w streamed dwordx4 from L2, A/B one-quad-ahead pipeline,
// per-lane sign fold (lanes>=32: fma(x,-1,-w) = -(x+w), exact), LDS combine.
// 256 blocks = 1 block/CU, 2 waves/SIMD.

#define FEAT  512
#define UNITS 256
#define BR    8          // rows per block
#define KW    64         // k per wave
#define NW    8          // waves per block
#define NQ    (KW / 4)   // 16 quads per wave

__device__ __forceinline__ float max3(float a, float b, float c) {
    return fmaxf(fmaxf(a, b), c);   // v_max3_f32
}

__device__ __forceinline__ void load_xquad(const float* __restrict__ lds, int kb, int q,
                                           float4* __restrict__ xb) {
    #pragma unroll
    for (int r = 0; r < BR; ++r)
        xb[r] = *(const float4*)&lds[r * FEAT + kb + q * 4];
}

__device__ __forceinline__ void load_wquad(const float* __restrict__ wp, int q,
                                           float4* __restrict__ wb) {
    #pragma unroll
    for (int k = 0; k < 4; ++k)
        wb[k] = *(const float4*)(wp + (size_t)(q * 4 + k) * UNITS);
}

__device__ __forceinline__ void compute_quad(const float4* __restrict__ xb,
                                             const float4* __restrict__ wq,
                                             float sgn, float4* __restrict__ acc) {
    // fold per-lane sign into w at use time (loads retired >= 1 quad ago)
    const float4 w0 = make_float4(wq[0].x*sgn, wq[0].y*sgn, wq[0].z*sgn, wq[0].w*sgn);
    const float4 w1 = make_float4(wq[1].x*sgn, wq[1].y*sgn, wq[1].z*sgn, wq[1].w*sgn);
    const float4 w2 = make_float4(wq[2].x*sgn, wq[2].y*sgn, wq[2].z*sgn, wq[2].w*sgn);
    const float4 w3 = make_float4(wq[3].x*sgn, wq[3].y*sgn, wq[3].z*sgn, wq[3].w*sgn);
    #pragma unroll
    for (int r = 0; r < BR; ++r) {
        const float4 a = xb[r];
        float4 A = acc[r];
        A.x = max3(A.x, fmaf(a.x, sgn, w0.x), fmaf(a.y, sgn, w1.x));
        A.x = max3(A.x, fmaf(a.z, sgn, w2.x), fmaf(a.w, sgn, w3.x));
        A.y = max3(A.y, fmaf(a.x, sgn, w0.y), fmaf(a.y, sgn, w1.y));
        A.y = max3(A.y, fmaf(a.z, sgn, w2.y), fmaf(a.w, sgn, w3.y));
        A.z = max3(A.z, fmaf(a.x, sgn, w0.z), fmaf(a.y, sgn, w1.z));
        A.z = max3(A.z, fmaf(a.z, sgn, w2.z), fmaf(a.w, sgn, w3.z));
        A.w = max3(A.w, fmaf(a.x, sgn, w0.w), fmaf(a.y, sgn, w1.w));
        A.w = max3(A.w, fmaf(a.z, sgn, w2.w), fmaf(a.w, sgn, w3.w));
        acc[r] = A;
    }
}

__global__ __launch_bounds__(512) void tropical_kernel(const float* __restrict__ x,
                                                       const float* __restrict__ w,
                                                       float* __restrict__ out) {
    __shared__ float lds[NW * BR * UNITS];   // 64 KB; x tile in first 16 KB
    const int tid  = threadIdx.x;
    const int lane = tid & 63;
    const int wv   = __builtin_amdgcn_readfirstlane(tid >> 6);  // 0..7
    const int u0   = lane * 4;                                  // 0..252
    const float sgn = (lane < 32) ? 1.0f : -1.0f;               // min half negated
    const int row0 = blockIdx.x * BR;
    const int kb   = wv * KW;

    // ---- stage x tile (8 rows x 512 = 16 KB), two float4 per thread ----
    {
        const float4* src = (const float4*)(x + (size_t)row0 * FEAT);
        ((float4*)lds)[tid]       = src[tid];
        ((float4*)lds)[tid + 512] = src[tid + 512];
    }

    const float* wp = w + (size_t)kb * UNITS + u0;

    float4 acc[BR];
    #pragma unroll
    for (int r = 0; r < BR; ++r)
        acc[r] = make_float4(-__builtin_inff(), -__builtin_inff(),
                             -__builtin_inff(), -__builtin_inff());

    // prologue w prefetch overlaps the staging barrier
    float4 xA[BR], xB[BR], wA[4], wB[4];
    load_wquad(wp, 0, wA);

    __syncthreads();   // x tile visible
    load_xquad(lds, kb, 0, xA);

    // ---- fully software-pipelined main loop: x AND w one quad ahead ----
    #pragma unroll 1
    for (int q = 0; q < NQ; q += 2) {
        load_wquad(wp, q + 1, wB);
        load_xquad(lds, kb, q + 1, xB);
        compute_quad(xA, wA, sgn, acc);      // covers the B-loads
        if (q + 2 < NQ) {
            load_wquad(wp, q + 2, wA);
            load_xquad(lds, kb, q + 2, xA);
        }
        compute_quad(xB, wB, sgn, acc);      // covers the A-loads
    }

    // ---- combine 8 k-partials via LDS (reuses x region; 64 KB) ----
    __syncthreads();   // all waves done reading x tile
    #pragma unroll
    for (int r = 0; r < BR; ++r)
        *(float4*)&lds[((wv * BR + r) * UNITS) + u0] = acc[r];   // lane-consecutive b128
    __syncthreads();

    // thread -> float4 of output: r = tid>>6 (0..7), units uo..uo+3
    const int r  = tid >> 6;
    const int uo = (tid & 63) * 4;
    float4 v = *(const float4*)&lds[(0 * BR + r) * UNITS + uo];
    #pragma unroll
    for (int j = 1; j < NW; ++j) {
        const float4 p = *(const float4*)&lds[(j * BR + r) * UNITS + uo];
        v.x = fmaxf(v.x, p.x);
        v.y = fmaxf(v.y, p.y);
        v.z = fmaxf(v.z, p.z);
        v.w = fmaxf(v.w, p.w);
    }
    const float so = (uo < 128) ? 1.0f : -1.0f;    // undo negation for min half
    *(float4*)&out[(size_t)(row0 + r) * UNITS + uo] =
        make_float4(v.x * so, v.y * so, v.z * so, v.w * so);
}

extern "C" void kernel_launch(void* const* d_in, const int* in_sizes, int n_in,
                              void* d_out, int out_size, void* d_ws, size_t ws_size,
                              hipStream_t stream) {
    const float* x = (const float*)d_in[0];   // (2048, 512)
    const float* w = (const float*)d_in[1];   // (512, 256)
    float* out = (float*)d_out;               // (2048, 256)

    // 256 blocks x 8 waves = 2048 waves = 2/SIMD, 1 block/CU; ILP-pipelined
    tropical_kernel<<<dim3(2048 / BR), dim3(512), 0, stream>>>(x, w, out);
}